// Round 24
// baseline (195.110 us; speedup 1.0000x reference)
//
#include <hip/hip_runtime.h>
#include <float.h>
#include <stdint.h>

#define DIM 512
#define BM 256   // fallback geometry only; main kernel uses 128x128 literals
#define NSPLIT 64
#define NUM_CLASSES 1000
#define MARGIN 0.5f   // fp8 screen: dot sigma ~0.05-0.08 -> ~6-sigma rescore margin

typedef unsigned short ushort_t;
typedef __attribute__((ext_vector_type(4))) float fvec4;
typedef __attribute__((ext_vector_type(8))) __bf16 bvec8;
typedef __attribute__((ext_vector_type(4))) int ivec4;
typedef __attribute__((ext_vector_type(8))) int ivec8;

#define AS1 __attribute__((address_space(1)))
#define AS3 __attribute__((address_space(3)))

__device__ inline ushort_t bf16_rne(float f) {
  uint32_t u = __builtin_bit_cast(uint32_t, f);
  uint32_t r = u + 0x7fffu + ((u >> 16) & 1u);
  return (ushort_t)(r >> 16);
}

// ---------- prep: rnorm + f32 -> fp8 e4m3 K128-BLOB array ----------
// Blob = 16 rows x 128 k of fp8 (2KB). Interior = lane-linear16 pairs:
//   lane l <-> (r=l&15, kc=l>>4); lo 16B at blob + l*16; hi 16B at blob+1024+l*16.
// Array: [row>>8][kc128 0..3][rowgrp 0..15][2048B]. Thread = (row, kc32).
__global__ __launch_bounds__(256) void prep_fp8(
    const float* __restrict__ src, float* __restrict__ rnorm_out,
    unsigned char* __restrict__ dst, int rows, int padRows, int scale) {
  int idx = blockIdx.x * 256 + threadIdx.x;
  if (idx >= padRows * 16) return;
  int row = idx >> 4, kc = idx & 15;
  int srow = min(row, rows - 1);             // pad rows replicate last row
  const float* s0 = src + (size_t)srow * DIM + kc * 32;
  float v[32];
  #pragma unroll
  for (int t = 0; t < 8; ++t) {
    float4 a = *(const float4*)(s0 + t * 4);
    v[4*t] = a.x; v[4*t+1] = a.y; v[4*t+2] = a.z; v[4*t+3] = a.w;
  }
  float rn = 1.0f;
  if (scale) {
    float s = 0.f;
    #pragma unroll
    for (int t = 0; t < 32; ++t) s += v[t] * v[t];
    #pragma unroll
    for (int off = 1; off < 16; off <<= 1) s += __shfl_xor(s, off, 64);
    rn = 1.0f / fmaxf(sqrtf(s), 1e-12f);
    if (rnorm_out && kc == 0 && row < rows) rnorm_out[row] = rn;
  }
  unsigned char* blob = dst + (((size_t)(row >> 8) * 4 + (kc >> 2)) * 16 + ((row >> 4) & 15)) * 2048;
  int lo_off = ((kc & 3) * 16 + (row & 15)) * 16;
  ivec4 lo4, hi4;
  #pragma unroll
  for (int t = 0; t < 4; ++t) {
    int wl = 0, wh = 0;
    wl = __builtin_amdgcn_cvt_pk_fp8_f32(v[4*t+0]*rn, v[4*t+1]*rn, wl, false);
    wl = __builtin_amdgcn_cvt_pk_fp8_f32(v[4*t+2]*rn, v[4*t+3]*rn, wl, true);
    wh = __builtin_amdgcn_cvt_pk_fp8_f32(v[16+4*t+0]*rn, v[16+4*t+1]*rn, wh, false);
    wh = __builtin_amdgcn_cvt_pk_fp8_f32(v[16+4*t+2]*rn, v[16+4*t+3]*rn, wh, true);
    lo4[t] = wl; hi4[t] = wh;
  }
  *(ivec4*)(blob + lo_off) = lo4;
  *(ivec4*)(blob + 1024 + lo_off) = hi4;
}

// ---------- screen (main): MX-scaled fp8 K=128, 4-wave 128x128 blocks ----------
// R23 failed with {stage-early, pointer-hoist, vector-bias} bundled; audits clean,
// so bisect from R22-verbatim (passed, 142.8us). R24 applies ONLY stage-early:
// STAGE(H+1) issued right after the barrier, before frag reads. Hazard proof:
// STAGE(H+1) writes buffer (H+1)&1, whose last readers (step H-1 frag reads)
// retired before every wave reached this step's barrier. Everything else is
// R22 text, unchanged. Banked: bias at FOLD only; split=(bx+8*by)&63;
// tile-exact splits.
__global__ __launch_bounds__(256)
__attribute__((amdgpu_waves_per_eu(2, 2)))
void nn_mx(
    const unsigned char* __restrict__ qb, const unsigned char* __restrict__ xb,
    int2* __restrict__ keys, int N) {
  __shared__ __align__(1024) char smem[65536];    // 2 buffers x (A 16KB | B 16KB)
  const int tid = threadIdx.x;
  const int l = tid & 63, w = tid >> 6;           // 4 waves
  const int wm = w >> 1, wn = w & 1;              // 2M x 2N; wave tile 64 x 64
  const int lrow = l & 15;
  const int totTiles = (N + 255) >> 8;            // 391
  const int split = (blockIdx.x + 8 * blockIdx.y) & (NSPLIT - 1);
  const int mb = blockIdx.y;                      // 16 m-blocks of 128 rows
  const int m0 = mb * 128;
  const int T0 = (totTiles * split) >> 6;
  const int T1 = (totTiles * (split + 1)) >> 6;
  const int nStart = T0 << 8;
  const int nEnd = min(T1 << 8, N);
  const int nSteps = (nEnd - nStart + 127) >> 7;  // 128-wide n-steps
  const int S = nSteps * 4;                       // 4 k128-steps each

  uint32_t K1[16], K2[16];
  #pragma unroll
  for (int s = 0; s < 16; ++s) { K1[s] = 0u; K2[s] = 0u; }

  // stage full buffer for step Hs: 4 A-loads + 4 B-loads per wave (1KB each)
  auto STAGE = [&](int Hs) {
    char* base = smem + (Hs & 1) * 32768;
    int n0 = nStart + (Hs >> 2) * 128;
    int kc128 = Hs & 3;
    #pragma unroll
    for (int t = 0; t < 2; ++t) {
      int g = 2 * w + t;
      int R = mb * 8 + g;                          // global A rowgrp
      const unsigned char* src = qb + (((size_t)(R >> 4) * 4 + kc128) * 16 + (R & 15)) * 2048;
      char* d = base + g * 2048;
      __builtin_amdgcn_global_load_lds((const AS1 int*)(src + l * 16), (AS3 int*)d, 16, 0, 0);
      __builtin_amdgcn_global_load_lds((const AS1 int*)(src + 1024 + l * 16), (AS3 int*)(d + 1024), 16, 0, 0);
    }
    int Tt = n0 >> 8, hi8 = (n0 >> 7) & 1;
    #pragma unroll
    for (int t = 0; t < 2; ++t) {
      int g = 2 * w + t;
      const unsigned char* src = xb + (((size_t)Tt * 4 + kc128) * 16 + hi8 * 8 + g) * 2048;
      char* d = base + 16384 + g * 2048;
      __builtin_amdgcn_global_load_lds((const AS1 int*)(src + l * 16), (AS3 int*)d, 16, 0, 0);
      __builtin_amdgcn_global_load_lds((const AS1 int*)(src + 1024 + l * 16), (AS3 int*)(d + 1024), 16, 0, 0);
    }
  };

  STAGE(0);   // prologue

  fvec4 acc[4][4];
  const fvec4 zero4 = {0.f, 0.f, 0.f, 0.f};       // bias at fold, NOT here

  #pragma unroll 1
  for (int H = 0; H < S; ++H) {
    if ((H & 3) == 0) {
      #pragma unroll
      for (int i = 0; i < 4; ++i)
        #pragma unroll
        for (int j = 0; j < 4; ++j) acc[i][j] = zero4;
    }
    const char* rb = smem + (H & 1) * 32768;

    // stage(H) complete + step H-1 readers retired -> safe to stage H+1 NOW
    asm volatile("s_waitcnt vmcnt(0)\n\ts_barrier" ::: "memory");
    __builtin_amdgcn_sched_barrier(0);
    if (H + 1 < S) STAGE(H + 1);    // ONLY change vs R22: issue before frag reads

    ivec8 Af[4], Bf[4];
    #pragma unroll
    for (int i = 0; i < 4; ++i) {
      const char* p = rb + (wm * 4 + i) * 2048 + l * 16;
      ivec4 alo = *(const ivec4*)p, ahi = *(const ivec4*)(p + 1024);
      Af[i] = __builtin_shufflevector(alo, ahi, 0, 1, 2, 3, 4, 5, 6, 7);
    }
    #pragma unroll
    for (int j = 0; j < 4; ++j) {
      const char* p = rb + 16384 + (wn * 4 + j) * 2048 + l * 16;
      ivec4 blo = *(const ivec4*)p, bhi = *(const ivec4*)(p + 1024);
      Bf[j] = __builtin_shufflevector(blo, bhi, 0, 1, 2, 3, 4, 5, 6, 7);
    }

    __builtin_amdgcn_s_setprio(1);
    #pragma unroll
    for (int i = 0; i < 4; ++i)
      #pragma unroll
      for (int j = 0; j < 4; ++j)
        acc[i][j] = __builtin_amdgcn_mfma_scale_f32_16x16x128_f8f6f4(
            Af[i], Bf[j], acc[i][j], 0, 0, 0, 127, 0, 127);
    __builtin_amdgcn_s_setprio(0);

    // ---- end of n-step: branchless top-2 fold (+8 bias applied HERE, scalar) ----
    if ((H & 3) == 3) {
      int n0 = nStart + (H >> 2) * 128;
      uint32_t msk[4], nb[4];
      #pragma unroll
      for (int j = 0; j < 4; ++j) {
        int n = n0 + wn * 64 + j * 16 + lrow;
        bool valid = n < nEnd;
        msk[j] = valid ? 0xFFFFF800u : 0u;
        nb[j]  = valid ? (uint32_t)(2047 - (n - nStart)) : 0u;
      }
      #pragma unroll
      for (int i = 0; i < 4; ++i)
        #pragma unroll
        for (int j = 0; j < 4; ++j)
          #pragma unroll
          for (int r = 0; r < 4; ++r) {
            int ss = i * 4 + r;
            uint32_t key = (__builtin_bit_cast(uint32_t, acc[i][j][r] + 8.0f) & msk[j]) | nb[j];
            uint32_t lo = min(K1[ss], key);
            K1[ss] = max(K1[ss], key);
            K2[ss] = max(K2[ss], lo);
          }
    }
  }

  // cross-lane top-2 merge over the 16 lanes sharing each query row
  #pragma unroll
  for (int s = 0; s < 16; ++s) {
    uint32_t k1 = K1[s], k2 = K2[s];
    #pragma unroll
    for (int off = 1; off < 16; off <<= 1) {
      uint32_t o1 = (uint32_t)__shfl_xor((int)k1, off, 64);
      uint32_t o2 = (uint32_t)__shfl_xor((int)k2, off, 64);
      uint32_t nk2 = max(min(k1, o1), max(k2, o2));
      k1 = max(k1, o1);
      k2 = nk2;
    }
    if (lrow == 0) {
      int m = m0 + wm * 64 + (s >> 2) * 16 + (l >> 4) * 4 + (s & 3);
      keys[((size_t)m * NSPLIT + split) * 2 + wn] = make_int2((int)k1, (int)k2);
    }
  }
}

// ---------- fallback (no-ws path): R13 structure, f32 -> bf16 on-the-fly ----------
__global__ __launch_bounds__(256)
__attribute__((amdgpu_waves_per_eu(2, 2)))
void nn_mfma_fb(
    const float* __restrict__ qf, const float* __restrict__ xf,
    const float* __restrict__ rnorm,
    int2* __restrict__ keys, int N) {
  __shared__ __align__(1024) char smem[49152];
  const int tid = threadIdx.x;
  const int l = tid & 63, wv = tid >> 6;
  const int lrow = l & 15;
  const int totTiles = (N + 255) >> 8;
  const int split = blockIdx.x;
  const int m0 = blockIdx.y * BM;
  const int nStart = ((totTiles * split) >> 6) << 8;
  const int nEnd = min(((totTiles * (split + 1)) >> 6) << 8, N);

  uint32_t K1[16], K2[16];
  #pragma unroll
  for (int s = 0; s < 16; ++s) { K1[s] = 0u; K2[s] = 0u; }
  const fvec4 zero4 = {0.f, 0.f, 0.f, 0.f};

  auto STAGE = [&](int c, int sn0, int sk0) {
    char* base = smem + c * 24576;
    #pragma unroll
    for (int u = 0; u < 6; ++u) {
      int unit = tid + 256 * u;
      if (unit < 1024) {
        int row = unit >> 2, kg = unit & 3;
        int boff_l = (row >> 4) * 1024 + kg * 256 + (row & 15) * 16;
        const float* s0 = qf + (size_t)(m0 + row) * DIM + sk0 + kg * 8;
        float4 a0 = *(const float4*)s0, a1 = *(const float4*)(s0 + 4);
        float vv[8] = {a0.x,a0.y,a0.z,a0.w,a1.x,a1.y,a1.z,a1.w};
        ivec4 hw;
        #pragma unroll
        for (int t = 0; t < 4; ++t) {
          ushort_t h0 = bf16_rne(vv[2*t]), h1 = bf16_rne(vv[2*t+1]);
          hw[t] = (int)((uint32_t)h0 | ((uint32_t)h1 << 16));
        }
        *(ivec4*)(base + boff_l) = hw;
      } else {
        int u2 = unit - 1024;
        int row = u2 >> 2, kg = u2 & 3;
        int boff_l = 16384 + (row >> 4) * 1024 + kg * 256 + (row & 15) * 16;
        int gr = min(sn0 + row, N - 1);
        float rn = rnorm[gr];
        const float* s0 = xf + (size_t)gr * DIM + sk0 + kg * 8;
        float4 a0 = *(const float4*)s0, a1 = *(const float4*)(s0 + 4);
        float vv[8] = {a0.x*rn,a0.y*rn,a0.z*rn,a0.w*rn,a1.x*rn,a1.y*rn,a1.z*rn,a1.w*rn};
        ivec4 hw;
        #pragma unroll
        for (int t = 0; t < 4; ++t) {
          ushort_t h0 = bf16_rne(vv[2*t]), h1 = bf16_rne(vv[2*t+1]);
          hw[t] = (int)((uint32_t)h0 | ((uint32_t)h1 << 16));
        }
        *(ivec4*)(base + boff_l) = hw;
      }
    }
  };

  const int nTiles = (nEnd - nStart + 127) >> 7;
  const int S = nTiles * 16;
  STAGE(0, nStart, 0);
  if (S > 1) STAGE(1 % 3, nStart, 32);
  __syncthreads();

  fvec4 acc[4][8];
  #pragma unroll 1
  for (int s = 0; s < S; ++s) {
    if ((s & 15) == 0) {
      #pragma unroll
      for (int i = 0; i < 4; ++i)
        #pragma unroll
        for (int j = 0; j < 8; ++j) acc[i][j] = zero4;
    }
    if (s + 2 < S) STAGE((s + 2) % 3, nStart + (((s + 2) >> 4) * 128), ((s + 2) & 15) * 32);
    const char* rb = smem + (s % 3) * 24576;
    bvec8 Ah[4], Bh[8];
    #pragma unroll
    for (int i = 0; i < 4; ++i)
      Ah[i] = __builtin_bit_cast(bvec8, *(const ivec4*)(rb + (wv*4 + i) * 1024 + l * 16));
    #pragma unroll
    for (int j = 0; j < 8; ++j)
      Bh[j] = __builtin_bit_cast(bvec8, *(const ivec4*)(rb + 16384 + j * 1024 + l * 16));
    #pragma unroll
    for (int i = 0; i < 4; ++i)
      #pragma unroll
      for (int j = 0; j < 8; ++j)
        acc[i][j] = __builtin_amdgcn_mfma_f32_16x16x32_bf16(Ah[i], Bh[j], acc[i][j], 0, 0, 0);
    if ((s & 15) == 15) {
      int n0 = nStart + ((s >> 4) * 128);
      uint32_t msk[8], nb[8];
      #pragma unroll
      for (int j = 0; j < 8; ++j) {
        int n = n0 + j * 16 + lrow;
        bool valid = n < nEnd;
        msk[j] = valid ? 0xFFFFF800u : 0u;
        nb[j]  = valid ? (uint32_t)(2047 - (n - nStart)) : 0u;
      }
      #pragma unroll
      for (int i = 0; i < 4; ++i)
        #pragma unroll
        for (int j = 0; j < 8; ++j)
          #pragma unroll
          for (int r = 0; r < 4; ++r) {
            int ss = i * 4 + r;
            uint32_t key = (__builtin_bit_cast(uint32_t, acc[i][j][r] + 8.0f) & msk[j]) | nb[j];
            uint32_t lo = min(K1[ss], key);
            K1[ss] = max(K1[ss], key);
            K2[ss] = max(K2[ss], lo);
          }
    }
    __syncthreads();
  }

  #pragma unroll
  for (int s = 0; s < 16; ++s) {
    uint32_t k1 = K1[s], k2 = K2[s];
    #pragma unroll
    for (int off = 1; off < 16; off <<= 1) {
      uint32_t o1 = (uint32_t)__shfl_xor((int)k1, off, 64);
      uint32_t o2 = (uint32_t)__shfl_xor((int)k2, off, 64);
      uint32_t nk2 = max(min(k1, o1), max(k2, o2));
      k1 = max(k1, o1);
      k2 = nk2;
    }
    if (lrow == 0) {
      int m = m0 + wv * 64 + (s >> 2) * 16 + (l >> 4) * 4 + (s & 3);
      keys[((size_t)m * NSPLIT + split) * 2 + 0] = make_int2((int)k1, (int)k2);
      keys[((size_t)m * NSPLIT + split) * 2 + 1] = make_int2(0, 0);
    }
  }
}

// ---------- finalize: unpack 256 candidate slots, exact f32 rescore, one-hot ----------
__global__ __launch_bounds__(256) void finalize_kernel(
    const int2* __restrict__ keys,
    const float* __restrict__ qf, const float* __restrict__ xf,
    const float* __restrict__ rnorm, const int* __restrict__ y,
    int* __restrict__ out, int N) {
  int m = blockIdx.x;
  int tid = threadIdx.x, l = tid & 63, w = tid >> 6;
  const int totTiles = (N + 255) >> 8;
  __shared__ float sv[256]; __shared__ int si[256];
  __shared__ float swm[4];
  __shared__ float swv[4]; __shared__ int swi[4];
  __shared__ int s_label;
  {
    int slot = tid >> 1;                       // split*2 + wn
    int2 kk = keys[(size_t)m * 128 + slot];
    uint32_t k = (tid & 1) ? (uint32_t)kk.y : (uint32_t)kk.x;
    float v; int idx;
    if (k == 0) { v = -FLT_MAX; idx = 0x7fffffff; }
    else {
      int sp = slot >> 1;
      int nStart = ((totTiles * sp) >> 6) << 8;
      v = __builtin_bit_cast(float, k & 0xFFFFF800u) - 8.0f;
      idx = nStart + 2047 - (int)(k & 0x7FFu);
    }
    sv[tid] = v; si[tid] = idx;
  }
  __syncthreads();
  float v = sv[tid];
  #pragma unroll
  for (int off = 1; off < 64; off <<= 1) v = fmaxf(v, __shfl_xor(v, off, 64));
  if (l == 0) swm[w] = v;
  __syncthreads();
  float svmax = fmaxf(fmaxf(swm[0], swm[1]), fmaxf(swm[2], swm[3]));
  float thresh = svmax - MARGIN;
  float bestv = -FLT_MAX; int besti = 0x7fffffff;
  for (int cc = 0; cc < 64; ++cc) {
    int c = w * 64 + cc;
    float av = sv[c]; int idx = si[c];
    if (av < thresh) continue;  // wave-uniform branch
    const float4* qp = (const float4*)(qf + (size_t)m * DIM);
    const float4* xp = (const float4*)(xf + (size_t)idx * DIM);
    float s = 0.f;
    #pragma unroll
    for (int t = 0; t < 2; ++t) {
      float4 qa = qp[l * 2 + t], xa = xp[l * 2 + t];
      s += qa.x*xa.x + qa.y*xa.y + qa.z*xa.z + qa.w*xa.w;
    }
    #pragma unroll
    for (int off = 1; off < 64; off <<= 1) s += __shfl_xor(s, off, 64);
    float ev = s * rnorm[idx];
    if (ev > bestv || (ev == bestv && idx < besti)) { bestv = ev; besti = idx; }
  }
  if (l == 0) { swv[w] = bestv; swi[w] = besti; }
  __syncthreads();
  if (tid == 0) {
    float bv = swv[0]; int bi = swi[0];
    #pragma unroll
    for (int k = 1; k < 4; ++k)
      if (swv[k] > bv || (swv[k] == bv && swi[k] < bi)) { bv = swv[k]; bi = swi[k]; }
    s_label = y[bi];
  }
  __syncthreads();
  int label = s_label;
  for (int c = tid; c < NUM_CLASSES; c += 256)
    out[(size_t)m * NUM_CLASSES + c] = (c == label) ? 1 : 0;
}

extern "C" void kernel_launch(void* const* d_in, const int* in_sizes, int n_in,
                              void* d_out, int out_size, void* d_ws, size_t ws_size,
                              hipStream_t stream) {
  const float* x = (const float*)d_in[0];   // [N, 512]
  const int*   y = (const int*)d_in[1];     // [N]
  const float* q = (const float*)d_in[2];   // [M, 512]
  int N = in_sizes[0] / DIM;                // 100000
  int M = in_sizes[2] / DIM;                // 2048
  int* out = (int*)d_out;
  int totTiles = (N + 255) >> 8;            // 391
  int padN = totTiles << 8;                 // 100096

  // workspace layout (fp8 blob arrays: ~52MB total)
  size_t off = 0;
  float* rnorm = (float*)((char*)d_ws + off); off += (((size_t)N * 4 + 1023) / 1024) * 1024;
  int2* keys   = (int2*)((char*)d_ws + off);  off += (size_t)M * NSPLIT * 2 * 8;
  unsigned char* qb8 = (unsigned char*)d_ws + off; off += (size_t)M * DIM;
  unsigned char* xb8 = (unsigned char*)d_ws + off; off += (size_t)padN * DIM;
  bool pre = (ws_size >= off);

  if (pre) {
    prep_fp8<<<(padN * 16 + 255) / 256, 256, 0, stream>>>(x, rnorm, xb8, N, padN, 1);
    prep_fp8<<<(M * 16 + 255) / 256, 256, 0, stream>>>(q, nullptr, qb8, M, M, 0);
    dim3 grid(NSPLIT, M / 128);               // 64 x 16 = 1024 blocks, 2/CU resident
    nn_mx<<<grid, 256, 0, stream>>>(qb8, xb8, keys, N);
  } else {
    prep_fp8<<<(N * 16 + 255) / 256, 256, 0, stream>>>(x, rnorm, nullptr, N, N, 1);
    dim3 gridf(NSPLIT, M / BM);               // fallback: bf16 on-the-fly
    nn_mfma_fb<<<gridf, 256, 0, stream>>>(q, x, rnorm, keys, N);
  }
  finalize_kernel<<<M, 256, 0, stream>>>(keys, q, x, rnorm, y, out, N);
}

// Round 25
// 190.169 us; speedup vs baseline: 1.0260x; 1.0260x over previous
//
#include <hip/hip_runtime.h>
#include <float.h>
#include <stdint.h>

#define DIM 512
#define BM 256   // fallback geometry only; main kernel uses 128x128 literals
#define NSPLIT 64
#define NUM_CLASSES 1000
#define MARGIN 0.5f   // fp8 screen: dot sigma ~0.05-0.08 -> ~6-sigma rescore margin

typedef unsigned short ushort_t;
typedef __attribute__((ext_vector_type(4))) float fvec4;
typedef __attribute__((ext_vector_type(8))) __bf16 bvec8;
typedef __attribute__((ext_vector_type(4))) int ivec4;
typedef __attribute__((ext_vector_type(8))) int ivec8;

#define AS1 __attribute__((address_space(1)))
#define AS3 __attribute__((address_space(3)))

__device__ inline ushort_t bf16_rne(float f) {
  uint32_t u = __builtin_bit_cast(uint32_t, f);
  uint32_t r = u + 0x7fffu + ((u >> 16) & 1u);
  return (ushort_t)(r >> 16);
}

// ---------- prep: rnorm + f32 -> fp8 e4m3 K128-BLOB array ----------
// Blob = 16 rows x 128 k of fp8 (2KB). Interior = lane-linear16 pairs:
//   lane l <-> (r=l&15, kc=l>>4); lo 16B at blob + l*16; hi 16B at blob+1024+l*16.
// Array: [row>>8][kc128 0..3][rowgrp 0..15][2048B]. Thread = (row, kc32).
__global__ __launch_bounds__(256) void prep_fp8(
    const float* __restrict__ src, float* __restrict__ rnorm_out,
    unsigned char* __restrict__ dst, int rows, int padRows, int scale) {
  int idx = blockIdx.x * 256 + threadIdx.x;
  if (idx >= padRows * 16) return;
  int row = idx >> 4, kc = idx & 15;
  int srow = min(row, rows - 1);             // pad rows replicate last row
  const float* s0 = src + (size_t)srow * DIM + kc * 32;
  float v[32];
  #pragma unroll
  for (int t = 0; t < 8; ++t) {
    float4 a = *(const float4*)(s0 + t * 4);
    v[4*t] = a.x; v[4*t+1] = a.y; v[4*t+2] = a.z; v[4*t+3] = a.w;
  }
  float rn = 1.0f;
  if (scale) {
    float s = 0.f;
    #pragma unroll
    for (int t = 0; t < 32; ++t) s += v[t] * v[t];
    #pragma unroll
    for (int off = 1; off < 16; off <<= 1) s += __shfl_xor(s, off, 64);
    rn = 1.0f / fmaxf(sqrtf(s), 1e-12f);
    if (rnorm_out && kc == 0 && row < rows) rnorm_out[row] = rn;
  }
  unsigned char* blob = dst + (((size_t)(row >> 8) * 4 + (kc >> 2)) * 16 + ((row >> 4) & 15)) * 2048;
  int lo_off = ((kc & 3) * 16 + (row & 15)) * 16;
  ivec4 lo4, hi4;
  #pragma unroll
  for (int t = 0; t < 4; ++t) {
    int wl = 0, wh = 0;
    wl = __builtin_amdgcn_cvt_pk_fp8_f32(v[4*t+0]*rn, v[4*t+1]*rn, wl, false);
    wl = __builtin_amdgcn_cvt_pk_fp8_f32(v[4*t+2]*rn, v[4*t+3]*rn, wl, true);
    wh = __builtin_amdgcn_cvt_pk_fp8_f32(v[16+4*t+0]*rn, v[16+4*t+1]*rn, wh, false);
    wh = __builtin_amdgcn_cvt_pk_fp8_f32(v[16+4*t+2]*rn, v[16+4*t+3]*rn, wh, true);
    lo4[t] = wl; hi4[t] = wh;
  }
  *(ivec4*)(blob + lo_off) = lo4;
  *(ivec4*)(blob + 1024 + lo_off) = hi4;
}

// ---------- screen (main): MX-scaled fp8 K=128, 4-wave 128x128 blocks ----------
// TERMINAL CONFIG = R22 verbatim (fastest passing: nn_mx 142.8us, total 190.4us).
// R24 bisect: stage-early innocent but not a win; R23's other changes
// (pointer-hoist, vector-bias) remain unexplained-failure territory -- not re-rolled.
// Structure: mfma_scale_f32_16x16x128_f8f6f4 (unit E8M0 scales = 127), wave tile
// 64x64, double-buffered 32KB buffers -> 64KB/block -> 2 blocks/CU (cross-block
// overlap covers the vmcnt(0) drain). Fragment reads: proven l*16 b128 pairs.
// Banked rules: +8 bias at FOLD only (bias-in-acc-init failed 2x);
// split=(bx+8*by)&63 (XCD locality); tile-exact variable splits.
__global__ __launch_bounds__(256)
__attribute__((amdgpu_waves_per_eu(2, 2)))
void nn_mx(
    const unsigned char* __restrict__ qb, const unsigned char* __restrict__ xb,
    int2* __restrict__ keys, int N) {
  __shared__ __align__(1024) char smem[65536];    // 2 buffers x (A 16KB | B 16KB)
  const int tid = threadIdx.x;
  const int l = tid & 63, w = tid >> 6;           // 4 waves
  const int wm = w >> 1, wn = w & 1;              // 2M x 2N; wave tile 64 x 64
  const int lrow = l & 15;
  const int totTiles = (N + 255) >> 8;            // 391
  const int split = (blockIdx.x + 8 * blockIdx.y) & (NSPLIT - 1);
  const int mb = blockIdx.y;                      // 16 m-blocks of 128 rows
  const int m0 = mb * 128;
  const int T0 = (totTiles * split) >> 6;
  const int T1 = (totTiles * (split + 1)) >> 6;
  const int nStart = T0 << 8;
  const int nEnd = min(T1 << 8, N);
  const int nSteps = (nEnd - nStart + 127) >> 7;  // 128-wide n-steps
  const int S = nSteps * 4;                       // 4 k128-steps each

  uint32_t K1[16], K2[16];
  #pragma unroll
  for (int s = 0; s < 16; ++s) { K1[s] = 0u; K2[s] = 0u; }

  // stage full buffer for step Hs: 4 A-loads + 4 B-loads per wave (1KB each)
  auto STAGE = [&](int Hs) {
    char* base = smem + (Hs & 1) * 32768;
    int n0 = nStart + (Hs >> 2) * 128;
    int kc128 = Hs & 3;
    #pragma unroll
    for (int t = 0; t < 2; ++t) {
      int g = 2 * w + t;
      int R = mb * 8 + g;                          // global A rowgrp
      const unsigned char* src = qb + (((size_t)(R >> 4) * 4 + kc128) * 16 + (R & 15)) * 2048;
      char* d = base + g * 2048;
      __builtin_amdgcn_global_load_lds((const AS1 int*)(src + l * 16), (AS3 int*)d, 16, 0, 0);
      __builtin_amdgcn_global_load_lds((const AS1 int*)(src + 1024 + l * 16), (AS3 int*)(d + 1024), 16, 0, 0);
    }
    int Tt = n0 >> 8, hi8 = (n0 >> 7) & 1;
    #pragma unroll
    for (int t = 0; t < 2; ++t) {
      int g = 2 * w + t;
      const unsigned char* src = xb + (((size_t)Tt * 4 + kc128) * 16 + hi8 * 8 + g) * 2048;
      char* d = base + 16384 + g * 2048;
      __builtin_amdgcn_global_load_lds((const AS1 int*)(src + l * 16), (AS3 int*)d, 16, 0, 0);
      __builtin_amdgcn_global_load_lds((const AS1 int*)(src + 1024 + l * 16), (AS3 int*)(d + 1024), 16, 0, 0);
    }
  };

  STAGE(0);   // prologue

  fvec4 acc[4][4];
  const fvec4 zero4 = {0.f, 0.f, 0.f, 0.f};       // bias at fold, NOT here

  #pragma unroll 1
  for (int H = 0; H < S; ++H) {
    if ((H & 3) == 0) {
      #pragma unroll
      for (int i = 0; i < 4; ++i)
        #pragma unroll
        for (int j = 0; j < 4; ++j) acc[i][j] = zero4;
    }
    const char* rb = smem + (H & 1) * 32768;

    // stage(H) complete + step H-1 readers retired -> safe to stage H+1
    asm volatile("s_waitcnt vmcnt(0)\n\ts_barrier" ::: "memory");
    __builtin_amdgcn_sched_barrier(0);

    ivec8 Af[4], Bf[4];
    #pragma unroll
    for (int i = 0; i < 4; ++i) {
      const char* p = rb + (wm * 4 + i) * 2048 + l * 16;
      ivec4 alo = *(const ivec4*)p, ahi = *(const ivec4*)(p + 1024);
      Af[i] = __builtin_shufflevector(alo, ahi, 0, 1, 2, 3, 4, 5, 6, 7);
    }
    #pragma unroll
    for (int j = 0; j < 4; ++j) {
      const char* p = rb + 16384 + (wn * 4 + j) * 2048 + l * 16;
      ivec4 blo = *(const ivec4*)p, bhi = *(const ivec4*)(p + 1024);
      Bf[j] = __builtin_shufflevector(blo, bhi, 0, 1, 2, 3, 4, 5, 6, 7);
    }
    if (H + 1 < S) STAGE(H + 1);

    __builtin_amdgcn_s_setprio(1);
    #pragma unroll
    for (int i = 0; i < 4; ++i)
      #pragma unroll
      for (int j = 0; j < 4; ++j)
        acc[i][j] = __builtin_amdgcn_mfma_scale_f32_16x16x128_f8f6f4(
            Af[i], Bf[j], acc[i][j], 0, 0, 0, 127, 0, 127);
    __builtin_amdgcn_s_setprio(0);

    // ---- end of n-step: branchless top-2 fold (+8 bias applied HERE) ----
    if ((H & 3) == 3) {
      int n0 = nStart + (H >> 2) * 128;
      uint32_t msk[4], nb[4];
      #pragma unroll
      for (int j = 0; j < 4; ++j) {
        int n = n0 + wn * 64 + j * 16 + lrow;
        bool valid = n < nEnd;
        msk[j] = valid ? 0xFFFFF800u : 0u;
        nb[j]  = valid ? (uint32_t)(2047 - (n - nStart)) : 0u;
      }
      #pragma unroll
      for (int i = 0; i < 4; ++i)
        #pragma unroll
        for (int j = 0; j < 4; ++j)
          #pragma unroll
          for (int r = 0; r < 4; ++r) {
            int ss = i * 4 + r;
            uint32_t key = (__builtin_bit_cast(uint32_t, acc[i][j][r] + 8.0f) & msk[j]) | nb[j];
            uint32_t lo = min(K1[ss], key);
            K1[ss] = max(K1[ss], key);
            K2[ss] = max(K2[ss], lo);
          }
    }
  }

  // cross-lane top-2 merge over the 16 lanes sharing each query row
  #pragma unroll
  for (int s = 0; s < 16; ++s) {
    uint32_t k1 = K1[s], k2 = K2[s];
    #pragma unroll
    for (int off = 1; off < 16; off <<= 1) {
      uint32_t o1 = (uint32_t)__shfl_xor((int)k1, off, 64);
      uint32_t o2 = (uint32_t)__shfl_xor((int)k2, off, 64);
      uint32_t nk2 = max(min(k1, o1), max(k2, o2));
      k1 = max(k1, o1);
      k2 = nk2;
    }
    if (lrow == 0) {
      int m = m0 + wm * 64 + (s >> 2) * 16 + (l >> 4) * 4 + (s & 3);
      keys[((size_t)m * NSPLIT + split) * 2 + wn] = make_int2((int)k1, (int)k2);
    }
  }
}

// ---------- fallback (no-ws path): R13 structure, f32 -> bf16 on-the-fly ----------
__global__ __launch_bounds__(256)
__attribute__((amdgpu_waves_per_eu(2, 2)))
void nn_mfma_fb(
    const float* __restrict__ qf, const float* __restrict__ xf,
    const float* __restrict__ rnorm,
    int2* __restrict__ keys, int N) {
  __shared__ __align__(1024) char smem[49152];
  const int tid = threadIdx.x;
  const int l = tid & 63, wv = tid >> 6;
  const int lrow = l & 15;
  const int totTiles = (N + 255) >> 8;
  const int split = blockIdx.x;
  const int m0 = blockIdx.y * BM;
  const int nStart = ((totTiles * split) >> 6) << 8;
  const int nEnd = min(((totTiles * (split + 1)) >> 6) << 8, N);

  uint32_t K1[16], K2[16];
  #pragma unroll
  for (int s = 0; s < 16; ++s) { K1[s] = 0u; K2[s] = 0u; }
  const fvec4 zero4 = {0.f, 0.f, 0.f, 0.f};

  auto STAGE = [&](int c, int sn0, int sk0) {
    char* base = smem + c * 24576;
    #pragma unroll
    for (int u = 0; u < 6; ++u) {
      int unit = tid + 256 * u;
      if (unit < 1024) {
        int row = unit >> 2, kg = unit & 3;
        int boff_l = (row >> 4) * 1024 + kg * 256 + (row & 15) * 16;
        const float* s0 = qf + (size_t)(m0 + row) * DIM + sk0 + kg * 8;
        float4 a0 = *(const float4*)s0, a1 = *(const float4*)(s0 + 4);
        float vv[8] = {a0.x,a0.y,a0.z,a0.w,a1.x,a1.y,a1.z,a1.w};
        ivec4 hw;
        #pragma unroll
        for (int t = 0; t < 4; ++t) {
          ushort_t h0 = bf16_rne(vv[2*t]), h1 = bf16_rne(vv[2*t+1]);
          hw[t] = (int)((uint32_t)h0 | ((uint32_t)h1 << 16));
        }
        *(ivec4*)(base + boff_l) = hw;
      } else {
        int u2 = unit - 1024;
        int row = u2 >> 2, kg = u2 & 3;
        int boff_l = 16384 + (row >> 4) * 1024 + kg * 256 + (row & 15) * 16;
        int gr = min(sn0 + row, N - 1);
        float rn = rnorm[gr];
        const float* s0 = xf + (size_t)gr * DIM + sk0 + kg * 8;
        float4 a0 = *(const float4*)s0, a1 = *(const float4*)(s0 + 4);
        float vv[8] = {a0.x*rn,a0.y*rn,a0.z*rn,a0.w*rn,a1.x*rn,a1.y*rn,a1.z*rn,a1.w*rn};
        ivec4 hw;
        #pragma unroll
        for (int t = 0; t < 4; ++t) {
          ushort_t h0 = bf16_rne(vv[2*t]), h1 = bf16_rne(vv[2*t+1]);
          hw[t] = (int)((uint32_t)h0 | ((uint32_t)h1 << 16));
        }
        *(ivec4*)(base + boff_l) = hw;
      }
    }
  };

  const int nTiles = (nEnd - nStart + 127) >> 7;
  const int S = nTiles * 16;
  STAGE(0, nStart, 0);
  if (S > 1) STAGE(1 % 3, nStart, 32);
  __syncthreads();

  fvec4 acc[4][8];
  #pragma unroll 1
  for (int s = 0; s < S; ++s) {
    if ((s & 15) == 0) {
      #pragma unroll
      for (int i = 0; i < 4; ++i)
        #pragma unroll
        for (int j = 0; j < 8; ++j) acc[i][j] = zero4;
    }
    if (s + 2 < S) STAGE((s + 2) % 3, nStart + (((s + 2) >> 4) * 128), ((s + 2) & 15) * 32);
    const char* rb = smem + (s % 3) * 24576;
    bvec8 Ah[4], Bh[8];
    #pragma unroll
    for (int i = 0; i < 4; ++i)
      Ah[i] = __builtin_bit_cast(bvec8, *(const ivec4*)(rb + (wv*4 + i) * 1024 + l * 16));
    #pragma unroll
    for (int j = 0; j < 8; ++j)
      Bh[j] = __builtin_bit_cast(bvec8, *(const ivec4*)(rb + 16384 + j * 1024 + l * 16));
    #pragma unroll
    for (int i = 0; i < 4; ++i)
      #pragma unroll
      for (int j = 0; j < 8; ++j)
        acc[i][j] = __builtin_amdgcn_mfma_f32_16x16x32_bf16(Ah[i], Bh[j], acc[i][j], 0, 0, 0);
    if ((s & 15) == 15) {
      int n0 = nStart + ((s >> 4) * 128);
      uint32_t msk[8], nb[8];
      #pragma unroll
      for (int j = 0; j < 8; ++j) {
        int n = n0 + j * 16 + lrow;
        bool valid = n < nEnd;
        msk[j] = valid ? 0xFFFFF800u : 0u;
        nb[j]  = valid ? (uint32_t)(2047 - (n - nStart)) : 0u;
      }
      #pragma unroll
      for (int i = 0; i < 4; ++i)
        #pragma unroll
        for (int j = 0; j < 8; ++j)
          #pragma unroll
          for (int r = 0; r < 4; ++r) {
            int ss = i * 4 + r;
            uint32_t key = (__builtin_bit_cast(uint32_t, acc[i][j][r] + 8.0f) & msk[j]) | nb[j];
            uint32_t lo = min(K1[ss], key);
            K1[ss] = max(K1[ss], key);
            K2[ss] = max(K2[ss], lo);
          }
    }
    __syncthreads();
  }

  #pragma unroll
  for (int s = 0; s < 16; ++s) {
    uint32_t k1 = K1[s], k2 = K2[s];
    #pragma unroll
    for (int off = 1; off < 16; off <<= 1) {
      uint32_t o1 = (uint32_t)__shfl_xor((int)k1, off, 64);
      uint32_t o2 = (uint32_t)__shfl_xor((int)k2, off, 64);
      uint32_t nk2 = max(min(k1, o1), max(k2, o2));
      k1 = max(k1, o1);
      k2 = nk2;
    }
    if (lrow == 0) {
      int m = m0 + wv * 64 + (s >> 2) * 16 + (l >> 4) * 4 + (s & 3);
      keys[((size_t)m * NSPLIT + split) * 2 + 0] = make_int2((int)k1, (int)k2);
      keys[((size_t)m * NSPLIT + split) * 2 + 1] = make_int2(0, 0);
    }
  }
}

// ---------- finalize: unpack 256 candidate slots, exact f32 rescore, one-hot ----------
__global__ __launch_bounds__(256) void finalize_kernel(
    const int2* __restrict__ keys,
    const float* __restrict__ qf, const float* __restrict__ xf,
    const float* __restrict__ rnorm, const int* __restrict__ y,
    int* __restrict__ out, int N) {
  int m = blockIdx.x;
  int tid = threadIdx.x, l = tid & 63, w = tid >> 6;
  const int totTiles = (N + 255) >> 8;
  __shared__ float sv[256]; __shared__ int si[256];
  __shared__ float swm[4];
  __shared__ float swv[4]; __shared__ int swi[4];
  __shared__ int s_label;
  {
    int slot = tid >> 1;                       // split*2 + wn
    int2 kk = keys[(size_t)m * 128 + slot];
    uint32_t k = (tid & 1) ? (uint32_t)kk.y : (uint32_t)kk.x;
    float v; int idx;
    if (k == 0) { v = -FLT_MAX; idx = 0x7fffffff; }
    else {
      int sp = slot >> 1;
      int nStart = ((totTiles * sp) >> 6) << 8;
      v = __builtin_bit_cast(float, k & 0xFFFFF800u) - 8.0f;
      idx = nStart + 2047 - (int)(k & 0x7FFu);
    }
    sv[tid] = v; si[tid] = idx;
  }
  __syncthreads();
  float v = sv[tid];
  #pragma unroll
  for (int off = 1; off < 64; off <<= 1) v = fmaxf(v, __shfl_xor(v, off, 64));
  if (l == 0) swm[w] = v;
  __syncthreads();
  float svmax = fmaxf(fmaxf(swm[0], swm[1]), fmaxf(swm[2], swm[3]));
  float thresh = svmax - MARGIN;
  float bestv = -FLT_MAX; int besti = 0x7fffffff;
  for (int cc = 0; cc < 64; ++cc) {
    int c = w * 64 + cc;
    float av = sv[c]; int idx = si[c];
    if (av < thresh) continue;  // wave-uniform branch
    const float4* qp = (const float4*)(qf + (size_t)m * DIM);
    const float4* xp = (const float4*)(xf + (size_t)idx * DIM);
    float s = 0.f;
    #pragma unroll
    for (int t = 0; t < 2; ++t) {
      float4 qa = qp[l * 2 + t], xa = xp[l * 2 + t];
      s += qa.x*xa.x + qa.y*xa.y + qa.z*xa.z + qa.w*xa.w;
    }
    #pragma unroll
    for (int off = 1; off < 64; off <<= 1) s += __shfl_xor(s, off, 64);
    float ev = s * rnorm[idx];
    if (ev > bestv || (ev == bestv && idx < besti)) { bestv = ev; besti = idx; }
  }
  if (l == 0) { swv[w] = bestv; swi[w] = besti; }
  __syncthreads();
  if (tid == 0) {
    float bv = swv[0]; int bi = swi[0];
    #pragma unroll
    for (int k = 1; k < 4; ++k)
      if (swv[k] > bv || (swv[k] == bv && swi[k] < bi)) { bv = swv[k]; bi = swi[k]; }
    s_label = y[bi];
  }
  __syncthreads();
  int label = s_label;
  for (int c = tid; c < NUM_CLASSES; c += 256)
    out[(size_t)m * NUM_CLASSES + c] = (c == label) ? 1 : 0;
}

extern "C" void kernel_launch(void* const* d_in, const int* in_sizes, int n_in,
                              void* d_out, int out_size, void* d_ws, size_t ws_size,
                              hipStream_t stream) {
  const float* x = (const float*)d_in[0];   // [N, 512]
  const int*   y = (const int*)d_in[1];     // [N]
  const float* q = (const float*)d_in[2];   // [M, 512]
  int N = in_sizes[0] / DIM;                // 100000
  int M = in_sizes[2] / DIM;                // 2048
  int* out = (int*)d_out;
  int totTiles = (N + 255) >> 8;            // 391
  int padN = totTiles << 8;                 // 100096

  // workspace layout (fp8 blob arrays: ~52MB total)
  size_t off = 0;
  float* rnorm = (float*)((char*)d_ws + off); off += (((size_t)N * 4 + 1023) / 1024) * 1024;
  int2* keys   = (int2*)((char*)d_ws + off);  off += (size_t)M * NSPLIT * 2 * 8;
  unsigned char* qb8 = (unsigned char*)d_ws + off; off += (size_t)M * DIM;
  unsigned char* xb8 = (unsigned char*)d_ws + off; off += (size_t)padN * DIM;
  bool pre = (ws_size >= off);

  if (pre) {
    prep_fp8<<<(padN * 16 + 255) / 256, 256, 0, stream>>>(x, rnorm, xb8, N, padN, 1);
    prep_fp8<<<(M * 16 + 255) / 256, 256, 0, stream>>>(q, nullptr, qb8, M, M, 0);
    dim3 grid(NSPLIT, M / 128);               // 64 x 16 = 1024 blocks, 2/CU resident
    nn_mx<<<grid, 256, 0, stream>>>(qb8, xb8, keys, N);
  } else {
    prep_fp8<<<(N * 16 + 255) / 256, 256, 0, stream>>>(x, rnorm, nullptr, N, N, 1);
    dim3 gridf(NSPLIT, M / BM);               // fallback: bf16 on-the-fly
    nn_mfma_fb<<<gridf, 256, 0, stream>>>(q, x, rnorm, keys, N);
  }
  finalize_kernel<<<M, 256, 0, stream>>>(keys, q, x, rnorm, y, out, N);
}